// Round 10
// baseline (415.047 us; speedup 1.0000x reference)
//
#include <hip/hip_runtime.h>
#include <hip/hip_bf16.h>
#include <cstdint>
#include <cstddef>

#define EPS 1e-8f
#define H_T 2.0794415416798357f /* ln(8) */
#define NUM_MARKED 4194304.0f   /* B*K: is_event is exactly one-hot over T */

typedef __attribute__((ext_vector_type(8))) short bf16x8;
typedef __attribute__((ext_vector_type(4))) float f32x4;

__device__ __forceinline__ unsigned short f2bf(float f) {
    union { float f; unsigned u; } v; v.f = f;
    unsigned r = v.u + 0x7fffu + ((v.u >> 16) & 1u);
    return (unsigned short)(r >> 16);
}

__device__ __forceinline__ void gl_lds16(const void* g, void* l) {
    __builtin_amdgcn_global_load_lds((const __attribute__((address_space(1))) unsigned int*)g,
                                     (__attribute__((address_space(3))) unsigned int*)l, 16, 0, 0);
}

// 64x64 f32->bf16 transpose tile. float4 loads, LDS [64][65], ushort4 stores.
__device__ __forceinline__ void transpose64(const float* __restrict__ in,
                                            unsigned short* __restrict__ out,
                                            int R, int C, int bx, int by,
                                            int tid, float* tile) {
    int c0 = bx * 64, r0 = by * 64;
    int row = tid >> 4, c4 = tid & 15;
#pragma unroll
    for (int i = 0; i < 4; i++) {
        float4 v = *(const float4*)(in + (size_t)(r0 + row + i * 16) * C + c0 + c4 * 4);
        float* t = tile + (row + i * 16) * 65 + c4 * 4;
        t[0] = v.x; t[1] = v.y; t[2] = v.z; t[3] = v.w;
    }
    __syncthreads();
    int rq = tid & 15, ccb = tid >> 4;
#pragma unroll
    for (int i = 0; i < 4; i++) {
        int cc = ccb + i * 16;
        ushort4 o;
        o.x = f2bf(tile[(rq * 4 + 0) * 65 + cc]);
        o.y = f2bf(tile[(rq * 4 + 1) * 65 + cc]);
        o.z = f2bf(tile[(rq * 4 + 2) * 65 + cc]);
        o.w = f2bf(tile[(rq * 4 + 3) * 65 + cc]);
        *(ushort4*)(out + (size_t)(c0 + cc) * R + r0 + rq * 4) = o;
    }
}

// ---------------- prep_lite: featbf + W1T ----------------
__global__ __launch_bounds__(256) void prep_lite(const float* __restrict__ features,
                                                 const float* __restrict__ W1,
                                                 unsigned short* __restrict__ featbf,
                                                 unsigned short* __restrict__ W1T,
                                                 float* __restrict__ accum) {
    __shared__ float tile[64 * 65];
    int bid = blockIdx.x, tid = threadIdx.x;
    if (bid < 192) {
        if (bid == 0 && tid < 8) accum[tid] = 0.0f;
        int i = (bid * 256 + tid) * 8;
        float4 a = *(const float4*)(features + i);
        float4 b = *(const float4*)(features + i + 4);
        ushort4 o0, o1;
        o0.x = f2bf(a.x); o0.y = f2bf(a.y); o0.z = f2bf(a.z); o0.w = f2bf(a.w);
        o1.x = f2bf(b.x); o1.y = f2bf(b.y); o1.z = f2bf(b.z); o1.w = f2bf(b.w);
        *(ushort4*)(featbf + i) = o0;
        *(ushort4*)(featbf + i + 4) = o1;
        return;
    }
    int b = bid - 192;
    transpose64(W1, W1T, 768, 4096, b & 63, b >> 6, tid, tile);
}

// ---------------- mid_kernel: GEMM1+bias || W2^T ----------------
__global__ __launch_bounds__(256) void mid_kernel(const unsigned short* __restrict__ A,   // featbf 512x768
                                                  const unsigned short* __restrict__ BT,  // W1T 4096x768
                                                  const float* __restrict__ bias,         // b1
                                                  float* __restrict__ C,                  // xbuf 512x4096
                                                  const float* __restrict__ W2,
                                                  unsigned short* __restrict__ W2T) {
    __shared__ union {
        struct { unsigned short lA[64 * 40]; unsigned short lB[64 * 40]; } g;
        float tile[64 * 65];
    } sm;
    int bid = blockIdx.x, tid = threadIdx.x;

    if (bid >= 512) {
        int b = bid - 512;
        transpose64(W2, W2T, 512, 8192, b & 127, b >> 7, tid, sm.tile);
        return;
    }

    // ---- gemm_bias: M=512, N=4096, K=768; 64x64 tile, 2x2 waves ----
    const int N = 4096, K = 768;
    int m0 = (bid & 7) * 64, n0 = (bid >> 3) * 64;
    int lane = tid & 63, wave = tid >> 6;
    int wm = wave >> 1, wn = wave & 1;
    int r = lane & 15, q = lane >> 4;

    f32x4 acc[2][2];
#pragma unroll
    for (int i = 0; i < 2; i++)
#pragma unroll
        for (int j = 0; j < 2; j++) acc[i][j] = (f32x4){0.f, 0.f, 0.f, 0.f};

    int ldrow = tid >> 2, ldc = (tid & 3) * 8;

    for (int kk = 0; kk < K; kk += 32) {
        uint4 av = *(const uint4*)(A + (size_t)(m0 + ldrow) * K + kk + ldc);
        uint4 bv = *(const uint4*)(BT + (size_t)(n0 + ldrow) * K + kk + ldc);
        __syncthreads();
        *(uint4*)(&sm.g.lA[ldrow * 40 + ldc]) = av;
        *(uint4*)(&sm.g.lB[ldrow * 40 + ldc]) = bv;
        __syncthreads();

        bf16x8 a0 = *(const bf16x8*)(&sm.g.lA[(wm * 32 + r) * 40 + q * 8]);
        bf16x8 a1 = *(const bf16x8*)(&sm.g.lA[(wm * 32 + 16 + r) * 40 + q * 8]);
        bf16x8 b0 = *(const bf16x8*)(&sm.g.lB[(wn * 32 + r) * 40 + q * 8]);
        bf16x8 b1 = *(const bf16x8*)(&sm.g.lB[(wn * 32 + 16 + r) * 40 + q * 8]);
        acc[0][0] = __builtin_amdgcn_mfma_f32_16x16x32_bf16(a0, b0, acc[0][0], 0, 0, 0);
        acc[0][1] = __builtin_amdgcn_mfma_f32_16x16x32_bf16(a0, b1, acc[0][1], 0, 0, 0);
        acc[1][0] = __builtin_amdgcn_mfma_f32_16x16x32_bf16(a1, b0, acc[1][0], 0, 0, 0);
        acc[1][1] = __builtin_amdgcn_mfma_f32_16x16x32_bf16(a1, b1, acc[1][1], 0, 0, 0);
    }

#pragma unroll
    for (int i = 0; i < 2; i++)
#pragma unroll
        for (int j = 0; j < 2; j++)
#pragma unroll
            for (int reg = 0; reg < 4; reg++) {
                int row = m0 + wm * 32 + i * 16 + q * 4 + reg;
                int col = n0 + wn * 32 + j * 16 + r;
                C[(size_t)row * N + col] = acc[i][j][reg] + bias[col];
            }
}

// ---------------- RMSNorm ----------------
__global__ __launch_bounds__(256) void rms_kernel(const float* __restrict__ x,
                                                  const float* __restrict__ norm_w,
                                                  unsigned short* __restrict__ xn) {
    int m = blockIdx.x;
    int tid = threadIdx.x;
    const float* row = x + (size_t)m * 512;
    float v0 = row[tid];
    float v1 = row[tid + 256];
    float ss = v0 * v0 + v1 * v1;
#pragma unroll
    for (int o = 32; o > 0; o >>= 1) ss += __shfl_down(ss, o);
    __shared__ float rs[4];
    __shared__ float scale_sh;
    int lane = tid & 63, wave = tid >> 6;
    if (lane == 0) rs[wave] = ss;
    __syncthreads();
    if (tid == 0) {
        float tot = rs[0] + rs[1] + rs[2] + rs[3];
        scale_sh = 1.0f / sqrtf(tot * (1.0f / 512.0f) + 1e-6f);
    }
    __syncthreads();
    float s = scale_sh;
    xn[(size_t)m * 512 + tid] = f2bf(v0 * s * norm_w[tid]);
    xn[(size_t)m * 512 + tid + 256] = f2bf(v1 * s * norm_w[tid + 256]);
}

// ---------------- GEMM2 + in-pipeline gl_lds compress + softmax/cumsum/loss ----------------
// M=4096, N=8192, K=512. BM=BN=128, BK=64, 256 threads = 4 waves (2x2).
// R10 (R9 post-mortem: serial pre-phase compress cost +70 us): compress
// t-slab t is staged via gl_lds (HOMOGENEOUS counted stream — R8's failure
// was counting compiler-managed register loads; gl_lds ops are exactly
// countable) into a single 16 KB chunk buffer, consumed between the two
// MFMA half-steps of iteration t, refilled after the barrier.
// Queue invariant per iteration: [T_t(8), C_t(4), T_{t+1}(8)] = 20
// -> uniform vmcnt(8) (same count as the proven R5 pipeline).
// lgkmcnt(0) before the trailing barrier guards chunk-read-vs-DMA-refill
// (single buffer; each wave reads/writes only its own region).
// is_cens: register-loaded at kernel start, pinned with a fake-use asm so
// the loads cannot sink into the counted region.
__global__ __launch_bounds__(256, 2) void gemm_loss(const unsigned short* __restrict__ A,
                                                    const unsigned short* __restrict__ BT,
                                                    const int* __restrict__ is_event,
                                                    const int* __restrict__ is_cens,
                                                    const float* __restrict__ ratio,
                                                    float* __restrict__ accum) {
    const int K = 512, NK = 8192;
    __shared__ union {
        unsigned short stage[2][2][8192];   // 64 KB: [dbuf][A/B][row*8 + kc16] 16B units
        float lg[128 * 128];                // 64 KB logit tile (stride 128)
    } sm;
    __shared__ union {
        struct { int ev[2048]; float rt[2048]; } c;                              // 16 KB chunk
        struct { float csel[2048]; unsigned short cpk[2048]; float rsum[4]; } e; // 12.3 KB epilogue
    } sc;

    int m0 = blockIdx.x * 128, n0 = blockIdx.y * 128;
    int tid = threadIdx.x;
    int lane = tid & 63, wave = tid >> 6;
    int wm = wave >> 1, wn = wave & 1;
    int r = lane & 15, q = lane >> 4;

    // compress ownership: blw = tid>>4 (b-row), cols {c4v..c4v+3} u {64+c4v..+3}
    int blw = tid >> 4;
    int c4v = (tid & 15) * 4;
    int b0 = m0 >> 3;

    // ---- is_cens: register loads, pinned BEFORE the counted gl_lds stream ----
    int cenpack;
    {
        const int* cnp = is_cens + (size_t)(b0 + blw) * NK + n0;
        int4 cen0 = *(const int4*)(cnp + c4v);
        int4 cen1 = *(const int4*)(cnp + 64 + c4v);
        cenpack = (cen0.x != 0) | ((cen0.y != 0) << 1) | ((cen0.z != 0) << 2) | ((cen0.w != 0) << 3)
                | ((cen1.x != 0) << 4) | ((cen1.y != 0) << 5) | ((cen1.z != 0) << 6) | ((cen1.w != 0) << 7);
        asm volatile("" :: "v"(cenpack));                       // pin load+pack here
        asm volatile("s_waitcnt vmcnt(0)" ::: "memory");        // counted stream starts at 0
    }

    int tevr[8]; float rslr[8];
#pragma unroll
    for (int j = 0; j < 8; j++) { tevr[j] = 0; rslr[j] = 0.0f; }

    f32x4 acc[4][4];
#pragma unroll
    for (int i = 0; i < 4; i++)
#pragma unroll
        for (int j = 0; j < 4; j++) acc[i][j] = (f32x4){0.f, 0.f, 0.f, 0.f};

    // LDS slot e (16B) of matrix X holds X[row=e>>3][K-chunk (e&7)^(row&7)]
    auto STAGE = [&](int buf, int kk) {
#pragma unroll
        for (int inst = 0; inst < 4; inst++) {
            int e = inst * 256 + tid;
            int row = e >> 3;
            int sc_ = (e & 7) ^ (row & 7);
            gl_lds16(A + (size_t)(m0 + row) * K + kk + sc_ * 8,
                     (char*)sm.stage[buf][0] + e * 16);
        }
#pragma unroll
        for (int inst = 0; inst < 4; inst++) {
            int e = inst * 256 + tid;
            int row = e >> 3;
            int sc_ = (e & 7) ^ (row & 7);
            gl_lds16(BT + (size_t)(n0 + row) * K + kk + sc_ * 8,
                     (char*)sm.stage[buf][1] + e * 16);
        }
    };

    // stage t-slab t of is_event/ratio: 4 gl_lds/thread, each op = 16 lines (floor)
    auto STAGEC = [&](int t) {
        const int*   evsrc = is_event + ((size_t)(b0 + blw) * 8 + t) * NK + n0;
        const float* rtsrc = ratio    + ((size_t)(b0 + blw) * 8 + t) * NK + n0;
        gl_lds16(evsrc + c4v,      (char*)sc.c.ev + tid * 16);
        gl_lds16(evsrc + 64 + c4v, (char*)sc.c.ev + 4096 + tid * 16);
        gl_lds16(rtsrc + c4v,      (char*)sc.c.rt + tid * 16);
        gl_lds16(rtsrc + 64 + c4v, (char*)sc.c.rt + 4096 + tid * 16);
    };

    auto CONSUME = [&](int t) {
        int4   e0 = *(const int4*)((const char*)sc.c.ev + tid * 16);
        int4   e1 = *(const int4*)((const char*)sc.c.ev + 4096 + tid * 16);
        float4 r0 = *(const float4*)((const char*)sc.c.rt + tid * 16);
        float4 r1 = *(const float4*)((const char*)sc.c.rt + 4096 + tid * 16);
        int   vv[8] = {e0.x, e0.y, e0.z, e0.w, e1.x, e1.y, e1.z, e1.w};
        float rr[8] = {r0.x, r0.y, r0.z, r0.w, r1.x, r1.y, r1.z, r1.w};
#pragma unroll
        for (int j = 0; j < 8; j++) {
            bool e_ = vv[j] != 0;
            tevr[j] = e_ ? t : tevr[j];
            rslr[j] = e_ ? rr[j] : rslr[j];
        }
    };

    auto COMPUTE_H = [&](int buf, int ks) {
        bf16x8 a[4], b[4];
#pragma unroll
        for (int i = 0; i < 4; i++) {
            int row = wm * 64 + i * 16 + r;
            int c = (ks * 4 + q) ^ (r & 7);
            a[i] = *(const bf16x8*)((const char*)sm.stage[buf][0] + ((size_t)row * 8 + c) * 16);
        }
#pragma unroll
        for (int j = 0; j < 4; j++) {
            int row = wn * 64 + j * 16 + r;
            int c = (ks * 4 + q) ^ (r & 7);
            b[j] = *(const bf16x8*)((const char*)sm.stage[buf][1] + ((size_t)row * 8 + c) * 16);
        }
        __builtin_amdgcn_s_setprio(1);
#pragma unroll
        for (int i = 0; i < 4; i++)
#pragma unroll
            for (int j = 0; j < 4; j++)
                acc[i][j] = __builtin_amdgcn_mfma_f32_16x16x32_bf16(a[i], b[j], acc[i][j], 0, 0, 0);
        __builtin_amdgcn_s_setprio(0);
    };

#define WAITV8 asm volatile("s_waitcnt vmcnt(8)" ::: "memory")
#define WAITV0 asm volatile("s_waitcnt vmcnt(0)" ::: "memory")
#define WAITL0 asm volatile("s_waitcnt lgkmcnt(0)" ::: "memory")
#define BARR __builtin_amdgcn_s_barrier()

    // prologue: queue = [T0(8), C0(4), T1(8)] = 20
    STAGE(0, 0);
    STAGEC(0);
    STAGE(1, 64);

#pragma unroll
    for (int t = 0; t < 8; t++) {
        if (t < 7) { WAITV8; }       // T_t + C_t landed; T_{t+1} stays in flight
        else       { WAITV0; }
        BARR;                        // tile t visible to all waves
        COMPUTE_H(t & 1, 0);
        CONSUME(t);                  // chunk t (own-wave data, visible after our wait)
        COMPUTE_H(t & 1, 1);
        WAITL0;                      // chunk/tile ds_reads drained before refill DMA
        BARR;                        // all waves done reading buf t&1
        if (t + 1 < 8) STAGEC(t + 1);            // C before T keeps queue invariant
        if (t + 2 < 8) STAGE(t & 1, (t + 2) * 64);
    }

    // ---- epilogue: write compressed pairs (chunk region now dead) + logit tile ----
#pragma unroll
    for (int j = 0; j < 8; j++) {
        int kl = (j < 4) ? (c4v + j) : (64 + c4v + j - 4);
        int p = blw * 128 + kl;
        sc.e.cpk[p]  = (unsigned short)(tevr[j] | (((cenpack >> j) & 1) << 3));
        sc.e.csel[p] = rslr[j];
    }
#pragma unroll
    for (int i = 0; i < 4; i++)
#pragma unroll
        for (int j = 0; j < 4; j++)
#pragma unroll
            for (int reg = 0; reg < 4; reg++) {
                int row = wm * 64 + i * 16 + q * 4 + reg;
                int col = wn * 64 + j * 16 + r;
                sm.lg[row * 128 + col] = acc[i][j][reg];
            }
    __syncthreads();

    float lsum = 0.0f;
#pragma unroll
    for (int p = 0; p < 8; p++) {
        int idx = tid + p * 256;            // 2048 (b,k) pairs per block
        int bl = idx >> 7, kl = idx & 127;

        int pk = sc.e.cpk[idx];
        float rsl = sc.e.csel[idx];
        int tev = pk & 7;
        bool cen = (pk & 8) != 0;

        float L[8];
#pragma unroll
        for (int t = 0; t < 8; t++) L[t] = sm.lg[(bl * 8 + t) * 128 + kl];
        float mx = L[0];
#pragma unroll
        for (int t = 1; t < 8; t++) mx = fmaxf(mx, L[t]);
        float e[8], s = 0.0f;
#pragma unroll
        for (int t = 0; t < 8; t++) { e[t] = __expf(L[t] - mx); s += e[t]; }
        float inv = 1.0f / s;

        float cum = 0.0f, pte = 0.0f, ite = 0.0f;
#pragma unroll
        for (int t = 0; t < 8; t++) {
            float pt = e[t] * inv;
            float integ = 1.0f - cum;
            cum += pt;
            bool hit = (t == tev);
            pte = hit ? pt : pte;
            ite = hit ? integ : ite;
        }
        float ps  = fminf(fmaxf(pte, EPS), 1.0f - EPS);
        float is0 = fminf(fmaxf(ite, EPS), 1.0f - EPS);
        float isc = fminf(fmaxf(is0 - rsl * ps, EPS), 1.0f - EPS);
        float val = cen ? isc : ps;
        lsum += logf(val);
    }

    // block reduction (4 waves)
#pragma unroll
    for (int o = 32; o > 0; o >>= 1) lsum += __shfl_down(lsum, o);
    if (lane == 0) sc.e.rsum[wave] = lsum;
    __syncthreads();
    if (tid == 0) {
        atomicAdd(&accum[0], sc.e.rsum[0] + sc.e.rsum[1] + sc.e.rsum[2] + sc.e.rsum[3]);
    }
}

__global__ void finalize_kernel(const float* __restrict__ accum, float* __restrict__ out) {
    out[0] = -accum[0] / (NUM_MARKED * H_T);
}

extern "C" void kernel_launch(void* const* d_in, const int* in_sizes, int n_in,
                              void* d_out, int out_size, void* d_ws, size_t ws_size,
                              hipStream_t stream) {
    const float* features = (const float*)d_in[0]; // 512x768
    const float* W1       = (const float*)d_in[1]; // 768x4096
    const float* b1       = (const float*)d_in[2]; // 4096
    const float* norm_w   = (const float*)d_in[3]; // 512
    const float* W2       = (const float*)d_in[4]; // 512x8192
    /* b2 (d_in[5]) is softmax(axis=1)-invariant: skipped */
    const int* is_event   = (const int*)d_in[6];   // 512x8x8192 (bool as i32)
    const int* is_cens    = (const int*)d_in[7];   // 512x8192  (bool as i32)
    const float* ratio    = (const float*)d_in[8]; // 512x8x8192
    float* out = (float*)d_out;

    char* ws = (char*)d_ws;
    size_t off = 0;
    auto alloc = [&](size_t bytes) { void* p = ws + off; off = (off + bytes + 255) & ~(size_t)255; return p; };
    unsigned short* W1T    = (unsigned short*)alloc((size_t)4096 * 768 * 2);
    unsigned short* W2T    = (unsigned short*)alloc((size_t)8192 * 512 * 2);
    unsigned short* featbf = (unsigned short*)alloc((size_t)512 * 768 * 2);
    float*          xbuf   = (float*)alloc((size_t)512 * 4096 * 4);
    unsigned short* xn     = (unsigned short*)alloc((size_t)4096 * 512 * 2);
    float*          accum  = (float*)alloc(64);

    prep_lite<<<960, 256, 0, stream>>>(features, W1, featbf, W1T, accum);
    mid_kernel<<<1536, 256, 0, stream>>>(featbf, W1T, b1, xbuf, W2, W2T);
    rms_kernel<<<4096, 256, 0, stream>>>(xbuf, norm_w, xn);
    gemm_loss<<<dim3(4096 / 128, 8192 / 128), 256, 0, stream>>>(xn, W2T, is_event, is_cens, ratio, accum);
    finalize_kernel<<<1, 1, 0, stream>>>(accum, out);
}